// Round 6
// baseline (495.494 us; speedup 1.0000x reference)
//
#include <hip/hip_runtime.h>
#include <hip/hip_bf16.h>
#include <math.h>

// AttentionPooling: scores = tanh(x@W1+b1)@W2+b2; segment softmax over sorted
// `batch`; out[g,:] = sum_i w_i * x[i,:].
// N = in_sizes[1] (200000), D = 256, H = 128, G = out_size/256 (512).
//
// scores: split-bf16 MFMA (xh*wh + xh*wl + xl*wh, fp32 accum ~ 2^-17 rel),
// ZERO LDS / ZERO barriers: each lane loads its MFMA fragments directly from
// global (A converted in-register; W1 pre-split by prep_w1 into d_ws).
// pooling: seg_stats turns scores into softmax weights in-place; pool streams
// x in uniform row chunks, atomicAdd-flushing per-wave partials on segment
// boundaries (batch is sorted -> ~2 flushes per wave).

typedef __attribute__((ext_vector_type(4))) float f32x4;
typedef __attribute__((ext_vector_type(8))) short s16x8;
typedef __attribute__((ext_vector_type(8))) unsigned short u16x8;

#define MFMA16(A, B, C) __builtin_amdgcn_mfma_f32_16x16x32_bf16((A), (B), (C), 0, 0, 0)

__device__ __forceinline__ unsigned short f2bf_rne(float f) {
    unsigned int u = __float_as_uint(f);
    unsigned int r = u + 0x7FFFu + ((u >> 16) & 1u);
    return (unsigned short)(r >> 16);
}
__device__ __forceinline__ float bf2f(unsigned short h) {
    return __uint_as_float(((unsigned int)h) << 16);
}

// ---- zero the output (it is 0xAA-poisoned; pool accumulates atomically) ----
__global__ __launch_bounds__(256)
void zero_out(float* __restrict__ out, int n)
{
    int i = blockIdx.x * 256 + threadIdx.x;
    if (i < n) out[i] = 0.f;
}

// ---- prep: split W1[k][n] (256x128 fp32) into bh/bl[n][k] (128x256 bf16) ----
__global__ __launch_bounds__(256)
void prep_w1(const float* __restrict__ W1, unsigned short* __restrict__ bh,
             unsigned short* __restrict__ bl)
{
    for (int idx = blockIdx.x * 256 + threadIdx.x; idx < 128 * 256;
         idx += gridDim.x * 256) {
        int n = idx & 127, k = idx >> 7;          // reads coalesced over n
        float f = W1[(size_t)k * 128 + n];
        unsigned short h = f2bf_rne(f);
        bh[(size_t)n * 256 + k] = h;
        bl[(size_t)n * 256 + k] = f2bf_rne(f - bf2f(h));
    }
}

// ---- scores: barrier-free, LDS-free split-bf16 MFMA GEMM + fused MLP ----
__global__ __launch_bounds__(256, 4)
void scores_mfma(const float* __restrict__ x,
                 const unsigned short* __restrict__ bh,
                 const unsigned short* __restrict__ bl,
                 const float* __restrict__ b1, const float* __restrict__ W2,
                 const float* __restrict__ b2, float* __restrict__ scores, int N)
{
    const int tid  = threadIdx.x;
    const int wave = tid >> 6;
    const int lane = tid & 63;
    const int c    = lane & 15;   // n-col within tile / m-row within A frag
    const int q    = lane >> 4;   // k-quad
    const int rowBase = blockIdx.x * 128 + wave * 32;   // this wave's 32 rows

    f32x4 acc[2][8];
#pragma unroll
    for (int mt = 0; mt < 2; ++mt)
#pragma unroll
        for (int nt = 0; nt < 8; ++nt)
            acc[mt][nt] = (f32x4){0.f, 0.f, 0.f, 0.f};

    const int r0 = rowBase + c;          // row for mt=0
    const int r1 = rowBase + 16 + c;     // row for mt=1

#pragma unroll 2
    for (int k0 = 0; k0 < 256; k0 += 32) {
        // ---- A fragments straight from global, convert fp32->hi/lo bf16 ----
        s16x8 fah[2], fal[2];
#pragma unroll
        for (int mt = 0; mt < 2; ++mt) {
            int row = mt ? r1 : r0;
            f32x4 a0 = (f32x4){0.f, 0.f, 0.f, 0.f};
            f32x4 a1 = (f32x4){0.f, 0.f, 0.f, 0.f};
            if (row < N) {
                const float* p = x + (size_t)row * 256 + k0 + q * 8;
                a0 = *(const f32x4*)(p);
                a1 = *(const f32x4*)(p + 4);
            }
            float af[8];
            *(f32x4*)&af[0] = a0; *(f32x4*)&af[4] = a1;
            unsigned short ah[8], al[8];
#pragma unroll
            for (int j = 0; j < 4; ++j) {
                float v0 = af[2 * j], v1 = af[2 * j + 1];
                __hip_bfloat162 h2 = __float22bfloat162_rn(make_float2(v0, v1));
                ushort2 hu = *(ushort2*)&h2;
                float rr0 = v0 - bf2f(hu.x), rr1 = v1 - bf2f(hu.y);
                __hip_bfloat162 l2 = __float22bfloat162_rn(make_float2(rr0, rr1));
                ushort2 lu = *(ushort2*)&l2;
                ah[2 * j] = hu.x; ah[2 * j + 1] = hu.y;
                al[2 * j] = lu.x; al[2 * j + 1] = lu.y;
            }
            fah[mt] = *(s16x8*)ah;
            fal[mt] = *(s16x8*)al;
        }
        // ---- B fragments straight from global (pre-split, [n][k]) ----
#pragma unroll
        for (int nt = 0; nt < 8; ++nt) {
            const size_t boff = (size_t)(nt * 16 + c) * 256 + k0 + q * 8;
            s16x8 fbh = *(const s16x8*)(bh + boff);
            s16x8 fbl = *(const s16x8*)(bl + boff);
#pragma unroll
            for (int mt = 0; mt < 2; ++mt) {
                acc[mt][nt] = MFMA16(fah[mt], fbh, acc[mt][nt]);
                acc[mt][nt] = MFMA16(fah[mt], fbl, acc[mt][nt]);
                acc[mt][nt] = MFMA16(fal[mt], fbh, acc[mt][nt]);
            }
        }
    }

    // ---- epilogue: tanh, dot W2, width-16 reduce, store ----
    float b1v[8], w2v[8];
#pragma unroll
    for (int nt = 0; nt < 8; ++nt) {
        b1v[nt] = b1[nt * 16 + c];
        w2v[nt] = W2[nt * 16 + c];
    }
    const float bias2 = b2[0];

#pragma unroll
    for (int mt = 0; mt < 2; ++mt) {
#pragma unroll
        for (int reg = 0; reg < 4; ++reg) {
            float p = 0.f;
#pragma unroll
            for (int nt = 0; nt < 8; ++nt) {
                float v = acc[mt][nt][reg] + b1v[nt];
                float e = __expf(2.f * v);       // tanh(v) = 1 - 2/(e^{2v}+1)
                p += (1.f - 2.f / (e + 1.f)) * w2v[nt];
            }
#pragma unroll
            for (int off = 8; off > 0; off >>= 1)
                p += __shfl_xor(p, off, 16);
            if (c == 0) {
                int row = rowBase + mt * 16 + q * 4 + reg;
                if (row < N) scores[row] = p + bias2;
            }
        }
    }
}

__device__ __forceinline__ int lower_bound_dev(const int* __restrict__ b, int n, int v)
{
    int lo = 0, hi = n;
    while (lo < hi) {
        int mid = (lo + hi) >> 1;
        if (b[mid] < v) lo = mid + 1; else hi = mid;
    }
    return lo;
}

// ---- per-segment softmax stats; converts scores -> weights IN PLACE ----
__global__ __launch_bounds__(256)
void seg_stats(const int* __restrict__ batch, float* __restrict__ sw, int N)
{
    const int g = blockIdx.x;
    const int tid = threadIdx.x;
    __shared__ int se[2];
    __shared__ float red[4];
    __shared__ float bc[2];

    if (tid < 2) se[tid] = lower_bound_dev(batch, N, g + tid);
    __syncthreads();
    const int start = se[0], end = se[1];

    // max
    float m = -INFINITY;
    for (int i = start + tid; i < end; i += 256) m = fmaxf(m, sw[i]);
#pragma unroll
    for (int off = 32; off > 0; off >>= 1) m = fmaxf(m, __shfl_xor(m, off, 64));
    if ((tid & 63) == 0) red[tid >> 6] = m;
    __syncthreads();
    m = fmaxf(fmaxf(red[0], red[1]), fmaxf(red[2], red[3]));

    // denom
    float s = 0.f;
    for (int i = start + tid; i < end; i += 256) s += expf(sw[i] - m);
#pragma unroll
    for (int off = 32; off > 0; off >>= 1) s += __shfl_xor(s, off, 64);
    __syncthreads();
    if ((tid & 63) == 0) red[tid >> 6] = s;
    __syncthreads();
    if (tid == 0) {
        float d = red[0] + red[1] + red[2] + red[3];
        bc[0] = m;
        bc[1] = (d > 0.f) ? 1.f / d : 0.f;
    }
    __syncthreads();
    const float mm = bc[0], inv = bc[1];

    // weights in place
    for (int i = start + tid; i < end; i += 256)
        sw[i] = expf(sw[i] - mm) * inv;
}

// ---- pooling: uniform row chunks, per-wave running acc, atomic flush ----
#define PR 256   // rows per block
__global__ __launch_bounds__(1024)
void pool_kernel(const float* __restrict__ x, const int* __restrict__ batch,
                 const float* __restrict__ wgt, float* __restrict__ out, int N)
{
    const int tid   = threadIdx.x;
    const int fidx  = tid & 63;     // feature group (4 floats)
    const int wv    = tid >> 6;     // 0..15 (row slot)
    const int r0    = blockIdx.x * PR;
    const int rend  = min(r0 + PR, N);

    f32x4 acc = (f32x4){0.f, 0.f, 0.f, 0.f};
    int seg_cur = -1;

    for (int row = r0 + wv; row < rend; row += 16) {
        int seg = batch[row];                 // wave-uniform (64 lanes same addr)
        if (seg != seg_cur) {
            if (seg_cur >= 0) {
                float* dst = out + (size_t)seg_cur * 256 + fidx * 4;
                atomicAdd(dst + 0, acc.x); atomicAdd(dst + 1, acc.y);
                atomicAdd(dst + 2, acc.z); atomicAdd(dst + 3, acc.w);
            }
            acc = (f32x4){0.f, 0.f, 0.f, 0.f};
            seg_cur = seg;
        }
        float w = wgt[row];
        f32x4 v = *(const f32x4*)(x + (size_t)row * 256 + fidx * 4);
        acc.x = fmaf(w, v.x, acc.x);
        acc.y = fmaf(w, v.y, acc.y);
        acc.z = fmaf(w, v.z, acc.z);
        acc.w = fmaf(w, v.w, acc.w);
    }
    if (seg_cur >= 0) {
        float* dst = out + (size_t)seg_cur * 256 + fidx * 4;
        atomicAdd(dst + 0, acc.x); atomicAdd(dst + 1, acc.y);
        atomicAdd(dst + 2, acc.z); atomicAdd(dst + 3, acc.w);
    }
}

extern "C" void kernel_launch(void* const* d_in, const int* in_sizes, int n_in,
                              void* d_out, int out_size, void* d_ws, size_t ws_size,
                              hipStream_t stream) {
    const float* x     = (const float*)d_in[0];
    const int*   batch = (const int*)  d_in[1];
    const float* W1    = (const float*)d_in[2];
    const float* b1    = (const float*)d_in[3];
    const float* W2    = (const float*)d_in[4];
    const float* b2    = (const float*)d_in[5];
    float* out = (float*)d_out;

    const int N = in_sizes[1];          // 200000
    const int G = out_size / 256;       // 512

    // d_ws layout: [0, 800KB) scores/weights; [1MB, +64KB) bh; then bl.
    float* scores      = (float*)d_ws;
    unsigned short* bh = (unsigned short*)((char*)d_ws + (1 << 20));
    unsigned short* bl = bh + 128 * 256;

    zero_out<<<(out_size + 255) / 256, 256, 0, stream>>>(out, out_size);
    prep_w1<<<64, 256, 0, stream>>>(W1, bh, bl);
    const int mblocks = (N + 127) / 128;
    scores_mfma<<<mblocks, 256, 0, stream>>>(x, bh, bl, b1, W2, b2, scores, N);
    seg_stats<<<G, 256, 0, stream>>>(batch, scores, N);
    pool_kernel<<<(N + PR - 1) / PR, 1024, 0, stream>>>(x, batch, scores, out, N);
}